// Round 19
// baseline (5846.407 us; speedup 1.0000x reference)
//
#include <hip/hip_runtime.h>

#define Tn 64
#define Bn 512
#define Dn 512
#define Hn 2048

typedef __attribute__((ext_vector_type(8))) short s16x8;
typedef __attribute__((ext_vector_type(4))) float f32x4;
typedef __attribute__((ext_vector_type(4))) unsigned int u32x4;
typedef unsigned int u32;
typedef unsigned long long u64;
typedef unsigned short u16;

__device__ __forceinline__ u16 f2bf(float f) {
    u32 u = __builtin_bit_cast(u32, f);
    return (u16)((u + 0x7fffu + ((u >> 16) & 1u)) >> 16);
}
__device__ __forceinline__ float bf2f(u32 v) {
    return __builtin_bit_cast(float, v << 16);
}
__device__ __forceinline__ float tanh_fast(float x) {
    float e = __builtin_amdgcn_exp2f(x * 2.885390081777927f);
    return 1.0f - 2.0f * __builtin_amdgcn_rcpf(e + 1.0f);
}
__device__ __forceinline__ u32 agent_ld(const u32* p) {
    return __hip_atomic_load((u32*)p, __ATOMIC_RELAXED, __HIP_MEMORY_SCOPE_AGENT);
}
__device__ __forceinline__ void agent_st(u32* p, u32 v) {
    __hip_atomic_store(p, v, __ATOMIC_RELAXED, __HIP_MEMORY_SCOPE_AGENT);
}
__device__ __forceinline__ u32 get_xcc() {
    u32 x;
    asm volatile("s_getreg_b32 %0, hwreg(HW_REG_XCC_ID)" : "=s"(x));
    return x & 0xffu;
}
__device__ __forceinline__ u64 rt64() {
    u64 t;
    asm volatile("s_memrealtime %0\n\ts_waitcnt lgkmcnt(0)" : "=s"(t));
    return t;
}

// ---- bulk-data ops: XL=true -> XCD-local L2 (sc0); XL=false -> device scope ----
template<bool XL>
__device__ __forceinline__ void eld128(u32x4& d, u32 vo, const void* base) {
    if constexpr (XL)
        asm volatile("global_load_dwordx4 %0, %1, %2 sc0"
                     : "=v"(d) : "v"(vo), "s"(base) : "memory");
    else
        asm volatile("global_load_dwordx4 %0, %1, %2 sc0 sc1 nt"
                     : "=v"(d) : "v"(vo), "s"(base) : "memory");
}
template<bool XL>
__device__ __forceinline__ void eld32(u32& d, u32 vo, const void* base) {
    if constexpr (XL)
        asm volatile("global_load_dword %0, %1, %2 sc0"
                     : "=v"(d) : "v"(vo), "s"(base) : "memory");
    else
        asm volatile("global_load_dword %0, %1, %2 sc0 sc1 nt"
                     : "=v"(d) : "v"(vo), "s"(base) : "memory");
}
template<bool XL>
__device__ __forceinline__ void est64(void* pa, u64 v) {
    if constexpr (XL)
        asm volatile("global_store_dwordx2 %0, %1, off sc0" :: "v"(pa), "v"(v) : "memory");
    else
        asm volatile("global_store_dwordx2 %0, %1, off sc0 sc1" :: "v"(pa), "v"(v) : "memory");
}
template<bool XL>
__device__ __forceinline__ void est32(void* pa, u32 v) {
    if constexpr (XL)
        asm volatile("global_store_dword %0, %1, off sc0" :: "v"(pa), "v"(v) : "memory");
    else
        asm volatile("global_store_dword %0, %1, off sc0 sc1" :: "v"(pa), "v"(v) : "memory");
}

// ---- epoch flags: dual-publish (sc0 fast + agent fallback), signed-distance poll ----
template<bool XL>
__device__ __forceinline__ void flag_pub(u32* f, u32 v) {
    if constexpr (XL) {
        asm volatile("global_store_dword %0, %1, off sc0" :: "v"(f), "v"(v) : "memory");
    }
    agent_st(f, v);    // MALL truth (v12-proven path), same address/value
}
template<bool XL>
__device__ __forceinline__ void flag_poll(const u32* f, u32 tgt) {
    if constexpr (XL) {
        int spins = 0;
        for (;;) {
            u32 v;
            asm volatile("global_load_dword %0, %1, off sc0" : "=v"(v) : "v"(f) : "memory");
            asm volatile("s_waitcnt vmcnt(0)" : "+v"(v) :: "memory");
            if ((int)(v - tgt) >= 0) return;
            if ((++spins & 63) == 0) {
                if ((int)(agent_ld(f) - tgt) >= 0) return;   // fallback view
            }
            __builtin_amdgcn_s_sleep(1);
        }
    } else {
        while ((int)(agent_ld(f) - tgt) < 0) __builtin_amdgcn_s_sleep(1);
    }
}

// Pack W1 (512x2048) and W2 (2048x512), f32 row-major -> bf16 MFMA-B-fragment order.
__global__ void pack_w(const float* __restrict__ W1, const float* __restrict__ W2,
                       u16* __restrict__ w1p, u16* __restrict__ w2p) {
    const int i = blockIdx.x * 256 + threadIdx.x;
    const int e = i & 7;
    const int lane = (i >> 3) & 63;
    const int krem = ((lane >> 4) << 3) + e;
    const int ncol = lane & 15;
    {   // W1: K=512 (16 ktiles), N=2048 (128 ntiles)
        const int kt = (i >> 9) & 15, nt = i >> 13;
        const int k = (kt << 5) + krem, n = (nt << 4) + ncol;
        w1p[i] = f2bf(W1[k * Hn + n]);
    }
    {   // W2: K=2048 (64 ktiles), N=512 (32 ntiles)
        const int kt = (i >> 9) & 63, nt = i >> 15;
        const int k = (kt << 5) + krem, n = (nt << 4) + ncol;
        w2p[i] = f2bf(W2[k * Dn + n]);
    }
}

// ---- helpers (v9-proven) ----

template<bool XL>
__device__ __forceinline__ void stage_a(const u32* ybrC, char* ldsA, int tid) {
    u32x4 d0, d1;
    const u32 vo = (u32)(tid << 5);
    eld128<XL>(d0, vo, ybrC);
    eld128<XL>(d1, vo + 16u, ybrC);
    asm volatile("s_waitcnt vmcnt(0)" : "+v"(d0), "+v"(d1) :: "memory");
    const u32 row = (u32)(tid >> 5);
    const u32 dst = vo ^ ((row & 7u) << 4);
    *(u32x4*)(ldsA + dst) = d0;
    *(u32x4*)(ldsA + (dst ^ 16u)) = d1;
}

__device__ __forceinline__ void stage_a0(const float* y0, int c, char* ldsA, int tid) {
    const float4* yc = (const float4*)(y0 + (size_t)(c << 4) * Dn);
    #pragma unroll
    for (int it = 0; it < 4; ++it) {
        const int idx = (it << 9) + tid;            // over [16 rows][128 f4]
        const float4 v = yc[idx];
        const u32 row = (u32)idx >> 7;
        u64 pk = (u64)((u32)f2bf(v.x) | ((u32)f2bf(v.y) << 16)) |
                 ((u64)((u32)f2bf(v.z) | ((u32)f2bf(v.w) << 16)) << 32);
        const u32 dst = (row * 1024u + ((u32)(idx & 127) << 3)) ^ ((row & 7u) << 4);
        *(u64*)(ldsA + dst) = pk;
    }
}

__device__ __forceinline__ void gemm1(const char* ldsA, char* ldsH,
                                      const s16x8 (&w1r)[16], float bia,
                                      u32 abase, u32 aswz, int w, int l15, int kg) {
    f32x4 g1 = f32x4{bia, bia, bia, bia};
    #pragma unroll
    for (int kt = 0; kt < 16; ++kt) {
        const s16x8 a = *(const s16x8*)(ldsA + ((abase + ((u32)kt << 6)) ^ aswz));
        g1 = __builtin_amdgcn_mfma_f32_16x16x32_bf16(a, w1r[kt], g1, 0, 0, 0);
    }
    #pragma unroll
    for (int j = 0; j < 4; ++j) {
        const u32 row = (u32)((kg << 2) + j);
        const u32 bo = (row * 256u + (((u32)(w << 4) + (u32)l15) << 1)) ^ ((row & 7u) << 4);
        *(u16*)(ldsH + bo) = f2bf(tanh_fast(g1[j]));
    }
}

template<bool XL>
__device__ __forceinline__ void gemm2_store(const char* ldsH, char* kpC,
                                            const s16x8 (&w2r)[4][4],
                                            u32 hbase, u32 aswz, int w, int l15,
                                            int kg, int h) {
    f32x4 acc[4];
    #pragma unroll
    for (int c = 0; c < 4; ++c) acc[c] = f32x4{0.f, 0.f, 0.f, 0.f};
    #pragma unroll
    for (int ks2 = 0; ks2 < 4; ++ks2) {
        const s16x8 ha = *(const s16x8*)(ldsH + ((hbase + ((u32)ks2 << 6)) ^ aswz));
        #pragma unroll
        for (int c = 0; c < 4; ++c)
            acc[c] = __builtin_amdgcn_mfma_f32_16x16x32_bf16(ha, w2r[c][ks2], acc[c], 0, 0, 0);
    }
    // partial block (o, h): [32 cols][16 rows] bf16 col-major, 1 KB
    #pragma unroll
    for (int c = 0; c < 4; ++c) {
        const int nt = (w << 2) + c;
        const int o = nt >> 1;
        const int sc2 = ((nt & 1) << 4) + l15;
        u64 pk = (u64)((u32)f2bf(acc[c][0]) | ((u32)f2bf(acc[c][1]) << 16)) |
                 ((u64)((u32)f2bf(acc[c][2]) | ((u32)f2bf(acc[c][3]) << 16)) << 32);
        void* pa = kpC + (size_t)((o << 4) + h) * 1024 + (u32)((sc2 << 5) + (kg << 3));
        est64<XL>(pa, pk);
    }
}

// post-gather RK4 update + y_in broadcast (no loads here)
template<bool XL>
__device__ __forceinline__ void owner_update(int s, float& ys, float& ks, float& dtv,
                                             int brow, float sacc, u32* ybrC,
                                             const float* tt, float* out, float b2c,
                                             int colg, int sc, int rm, int h) {
    const int step = s >> 2, sub = s & 3;
    if (sub == 0)
        dtv = tt[(step + 1) * Bn + brow] - tt[step * Bn + brow];
    const float kk = dtv * (sacc + b2c);
    float yin;
    if (sub == 0)      { ks = kk;         yin = ys + 0.5f * kk; }
    else if (sub == 1) { ks += 2.f * kk;  yin = ys + 0.5f * kk; }
    else if (sub == 2) { ks += 2.f * kk;  yin = ys + kk; }
    else {
        ks += kk; ys += ks * (1.f / 6.f); yin = ys;
        __builtin_nontemporal_store(ys, &out[((step + 1) * Bn + brow) * Dn + colg]);
    }
    if (s < 251) {
        const u32 my = (u32)f2bf(yin);
        const u32 pu = (u32)__shfl_xor((int)my, 16, 64);
        if ((sc & 1) == 0) {
            u32* ba = ybrC + (rm << 8) + (h << 4) + (sc >> 1);
            est32<XL>(ba, my | (pu << 16));
        }
    }
}

// v19 loop: v18 + epoch-based flags (sc0 fast path, agent fallback).
template<bool XL>
__device__ __forceinline__ void ode_loop(
    const float* y0, const float* tt, float* out,
    char* A0, char* A1, char* H0, char* H1,
    const s16x8 (&w1r)[16], const s16x8 (&w2r)[4][4],
    float bia, float b2c, u32 abase, u32 aswz, u32 hbase,
    u32* ybr0, u32* ybr1, char* kp0, char* kp1,
    u32* fl1c0, u32* fl1c1, u32* fl2c0, u32* fl2c1,
    int c0, int c1, int brow0, int brow1, int colg,
    int tid, int w, int l15, int kg, int sc, int rm, int h,
    float ys0, float ys1, u32 E) {
    float ks0 = 0.f, ks1 = 0.f, dt0 = 0.f, dt1 = 0.f;
    #pragma unroll 1
    for (int s = 0; s < 252; ++s) {
        // ---- SYNC-A: both chunks' y_in ready; stage both A-tiles ----
        if (s == 0) {
            stage_a0(y0, c0, A0, tid);
            stage_a0(y0, c1, A1, tid);
        } else {
            if (tid < 32) {
                u32* f = (tid < 16) ? (fl2c0 + tid) : (fl2c1 + (tid & 15));
                flag_poll<XL>(f, E + (u32)s);
            }
            __syncthreads();
            stage_a<XL>(ybr0, A0, tid);
            stage_a<XL>(ybr1, A1, tid);
        }
        __syncthreads();
        // ---- GEMM1 both chunks ----
        gemm1(A0, H0, w1r, bia, abase, aswz, w, l15, kg);
        gemm1(A1, H1, w1r, bia, abase, aswz, w, l15, kg);
        __syncthreads();
        // ---- GEMM2 both chunks + partial stores; publish fl1 pair ----
        gemm2_store<XL>(H0, kp0, w2r, hbase, aswz, w, l15, kg, h);
        gemm2_store<XL>(H1, kp1, w2r, hbase, aswz, w, l15, kg, h);
        asm volatile("s_waitcnt vmcnt(0)" ::: "memory");
        __syncthreads();
        if (tid == 0) {
            flag_pub<XL>(fl1c0 + h, E + (u32)(s + 1));
            flag_pub<XL>(fl1c1 + h, E + (u32)(s + 1));
        }
        // ---- SYNC-B: all partials ready (one merged poll) ----
        if (tid < 32) {
            u32* f = (tid < 16) ? (fl1c0 + tid) : (fl1c1 + (tid & 15));
            flag_poll<XL>(f, E + (u32)(s + 1));
        }
        __syncthreads();
        // ---- batched gather (both chunks, split waitcnt) ----
        float sacc0 = 0.f, sacc1 = 0.f;
        {
            const u32 bo = ((u32)h << 14) + (u32)((sc << 5) + ((rm >> 1) << 2));
            u32 a0,a1,a2,a3,a4,a5,a6,a7,a8,a9,aa,ab,ac,ad,ae,af;
            u32 b0,b1,b2,b3,b4,b5,b6,b7,b8,b9,ba,bb,bc,bd,be,bf;
            eld32<XL>(a0, bo + (0u << 10), kp0);  eld32<XL>(a1, bo + (1u << 10), kp0);
            eld32<XL>(a2, bo + (2u << 10), kp0);  eld32<XL>(a3, bo + (3u << 10), kp0);
            eld32<XL>(a4, bo + (4u << 10), kp0);  eld32<XL>(a5, bo + (5u << 10), kp0);
            eld32<XL>(a6, bo + (6u << 10), kp0);  eld32<XL>(a7, bo + (7u << 10), kp0);
            eld32<XL>(a8, bo + (8u << 10), kp0);  eld32<XL>(a9, bo + (9u << 10), kp0);
            eld32<XL>(aa, bo + (10u << 10), kp0); eld32<XL>(ab, bo + (11u << 10), kp0);
            eld32<XL>(ac, bo + (12u << 10), kp0); eld32<XL>(ad, bo + (13u << 10), kp0);
            eld32<XL>(ae, bo + (14u << 10), kp0); eld32<XL>(af, bo + (15u << 10), kp0);
            eld32<XL>(b0, bo + (0u << 10), kp1);  eld32<XL>(b1, bo + (1u << 10), kp1);
            eld32<XL>(b2, bo + (2u << 10), kp1);  eld32<XL>(b3, bo + (3u << 10), kp1);
            eld32<XL>(b4, bo + (4u << 10), kp1);  eld32<XL>(b5, bo + (5u << 10), kp1);
            eld32<XL>(b6, bo + (6u << 10), kp1);  eld32<XL>(b7, bo + (7u << 10), kp1);
            eld32<XL>(b8, bo + (8u << 10), kp1);  eld32<XL>(b9, bo + (9u << 10), kp1);
            eld32<XL>(ba, bo + (10u << 10), kp1); eld32<XL>(bb, bo + (11u << 10), kp1);
            eld32<XL>(bc, bo + (12u << 10), kp1); eld32<XL>(bd, bo + (13u << 10), kp1);
            eld32<XL>(be, bo + (14u << 10), kp1); eld32<XL>(bf, bo + (15u << 10), kp1);
            asm volatile("s_waitcnt vmcnt(16)"
                         : "+v"(a0),"+v"(a1),"+v"(a2),"+v"(a3),
                           "+v"(a4),"+v"(a5),"+v"(a6),"+v"(a7),
                           "+v"(a8),"+v"(a9),"+v"(aa),"+v"(ab),
                           "+v"(ac),"+v"(ad),"+v"(ae),"+v"(af) :: "memory");
            const bool hi = (rm & 1);
#define ACCA(d) sacc0 += bf2f(hi ? ((d) >> 16) : ((d) & 0xffffu))
#define ACCB(d) sacc1 += bf2f(hi ? ((d) >> 16) : ((d) & 0xffffu))
            ACCA(a0); ACCA(a1); ACCA(a2); ACCA(a3);
            ACCA(a4); ACCA(a5); ACCA(a6); ACCA(a7);
            ACCA(a8); ACCA(a9); ACCA(aa); ACCA(ab);
            ACCA(ac); ACCA(ad); ACCA(ae); ACCA(af);
            asm volatile("s_waitcnt vmcnt(0)"
                         : "+v"(b0),"+v"(b1),"+v"(b2),"+v"(b3),
                           "+v"(b4),"+v"(b5),"+v"(b6),"+v"(b7),
                           "+v"(b8),"+v"(b9),"+v"(ba),"+v"(bb),
                           "+v"(bc),"+v"(bd),"+v"(be),"+v"(bf) :: "memory");
            ACCB(b0); ACCB(b1); ACCB(b2); ACCB(b3);
            ACCB(b4); ACCB(b5); ACCB(b6); ACCB(b7);
            ACCB(b8); ACCB(b9); ACCB(ba); ACCB(bb);
            ACCB(bc); ACCB(bd); ACCB(be); ACCB(bf);
#undef ACCA
#undef ACCB
        }
        // ---- RK4 update + broadcast, both chunks; publish fl2 pair ----
        owner_update<XL>(s, ys0, ks0, dt0, brow0, sacc0, ybr0,
                         tt, out, b2c, colg, sc, rm, h);
        owner_update<XL>(s, ys1, ks1, dt1, brow1, sacc1, ybr1,
                         tt, out, b2c, colg, sc, rm, h);
        if (s < 251) {
            asm volatile("s_waitcnt vmcnt(0)" ::: "memory");
            __syncthreads();
            if (tid == 0) {
                flag_pub<XL>(fl2c0 + h, E + (u32)(s + 1));
                flag_pub<XL>(fl2c1 + h, E + (u32)(s + 1));
            }
        }
    }
}

// v19: v18 + epoch-based XCD-local flags. 256 WGs = 16 pairs x 16 slices
// (p=bid&15 -> XCD pinning, runtime-verified).
__launch_bounds__(512, 2)
__global__ void ode_v19(const float* __restrict__ y0, const float* __restrict__ tt,
                        const float* __restrict__ b1, const float* __restrict__ b2,
                        const u16* __restrict__ w1p, const u16* __restrict__ w2p,
                        float* __restrict__ out, u16* __restrict__ ybuf,
                        u16* __restrict__ kpart, u32* __restrict__ flags1,
                        u32* __restrict__ flags2, u32* __restrict__ xslot,
                        u32* __restrict__ xmode, u32* __restrict__ xepoch) {
    __shared__ u16 lds_A0[16 * 512], lds_A1[16 * 512];   // 16KB each
    __shared__ u16 lds_H0[16 * 128], lds_H1[16 * 128];   // 4KB each
    __shared__ u32 smode, sepoch;
    char* A0 = (char*)lds_A0; char* A1 = (char*)lds_A1;
    char* H0 = (char*)lds_H0; char* H1 = (char*)lds_H1;

    const int tid = threadIdx.x;
    const int w = tid >> 6, lane = tid & 63, l15 = lane & 15, kg = lane >> 4;
    const int p = blockIdx.x & 15, h = blockIdx.x >> 4;   // pair -> XCD pinning
    const int c0 = p << 1, c1 = c0 + 1;

    // ---- runtime XCD-affinity detection + per-pair epoch (agent-scope) ----
    if (tid == 0) {
        agent_st(xslot + (p << 4) + h, get_xcc() + 1u);
        if (h == 0) {
            u32 ref = 0; bool same = true;
            #pragma unroll 1
            for (int i = 0; i < 16; ++i) {
                u32 v;
                while ((v = agent_ld(xslot + (p << 4) + i)) == 0u)
                    __builtin_amdgcn_s_sleep(1);
                if (i == 0) ref = v; else same = same && (v == ref);
            }
            const u32 E = (u32)(rt64() >> 6) | 1u;   // monotonic across replays
            agent_st(xepoch + p, E);
            __hip_atomic_store(xmode + p, same ? 1u : 2u,
                               __ATOMIC_RELEASE, __HIP_MEMORY_SCOPE_AGENT);
        }
        u32 m;
        while ((m = __hip_atomic_load(xmode + p, __ATOMIC_ACQUIRE,
                                      __HIP_MEMORY_SCOPE_AGENT)) == 0u)
            __builtin_amdgcn_s_sleep(1);
        smode = m;
        sepoch = agent_ld(xepoch + p);
    }

    const int sc = tid >> 4, rm = tid & 15;
    const int colg = (h << 5) + sc;
    const int brow0 = (c0 << 4) + rm, brow1 = (c1 << 4) + rm;
    const float b2c = b2[colg];
    float ys0 = y0[brow0 * Dn + colg];
    float ys1 = y0[brow1 * Dn + colg];
    __builtin_nontemporal_store(ys0, &out[brow0 * Dn + colg]);
    __builtin_nontemporal_store(ys1, &out[brow1 * Dn + colg]);

    // ---- weight preload into registers ----
    s16x8 w1r[16];
    #pragma unroll
    for (int kt = 0; kt < 16; ++kt)
        w1r[kt] = *(const s16x8*)&w1p[((size_t)((h << 3) + w) * 16 + kt) * 512 + (lane << 3)];
    s16x8 w2r[4][4];
    #pragma unroll
    for (int cc = 0; cc < 4; ++cc)
        #pragma unroll
        for (int ks2 = 0; ks2 < 4; ++ks2)
            w2r[cc][ks2] = *(const s16x8*)&w2p[((size_t)((w << 2) + cc) * 64 + (h << 2) + ks2) * 512 + (lane << 3)];
    const float bia = b1[(h << 7) + (w << 4) + l15];

    const u32 abase = (u32)l15 * 1024u + ((u32)kg << 4);
    const u32 aswz = ((u32)(l15 & 7)) << 4;
    const u32 hbase = (u32)l15 * 256u + ((u32)kg << 4);

    u32* ybr0 = (u32*)(ybuf + (size_t)c0 * 16 * 512);
    u32* ybr1 = (u32*)(ybuf + (size_t)c1 * 16 * 512);
    char* kp0 = (char*)kpart + (size_t)c0 * (256 * 1024);
    char* kp1 = (char*)kpart + (size_t)c1 * (256 * 1024);
    u32* fl1c0 = flags1 + (c0 << 4); u32* fl1c1 = flags1 + (c1 << 4);
    u32* fl2c0 = flags2 + (c0 << 4); u32* fl2c1 = flags2 + (c1 << 4);

    __syncthreads();
    const u32 mode = smode;
    const u32 E = sepoch;

    if (mode == 1u)
        ode_loop<true>(y0, tt, out, A0, A1, H0, H1, w1r, w2r, bia, b2c,
                       abase, aswz, hbase, ybr0, ybr1, kp0, kp1,
                       fl1c0, fl1c1, fl2c0, fl2c1, c0, c1, brow0, brow1, colg,
                       tid, w, l15, kg, sc, rm, h, ys0, ys1, E);
    else
        ode_loop<false>(y0, tt, out, A0, A1, H0, H1, w1r, w2r, bia, b2c,
                        abase, aswz, hbase, ybr0, ybr1, kp0, kp1,
                        fl1c0, fl1c1, fl2c0, fl2c1, c0, c1, brow0, brow1, colg,
                        tid, w, l15, kg, sc, rm, h, ys0, ys1, E);
}

// ---------------- fallback: round-1 kernel (32 WGs) ----------------
__launch_bounds__(512, 2)
__global__ void ode_rk4_fb(const float* __restrict__ y0, const float* __restrict__ tt,
                           const float* __restrict__ b1, const float* __restrict__ b2,
                           const u16* __restrict__ w1p, const u16* __restrict__ w2p,
                           float* __restrict__ out) {
    __shared__ u16 lds_ys[16 * Dn];
    __shared__ u16 lds_hid[16 * Hn];
    __shared__ float lds_dt[16];
    const int tid = threadIdx.x;
    const int w = tid >> 6, lane = tid & 63, l15 = lane & 15, kgrp = lane >> 4;
    const int row0 = blockIdx.x << 4;
    float yreg[4][4], ksum[4][4], kk[4][4];
    float b1v[16], b2v[4], dtv[4];
    #pragma unroll
    for (int nt = 0; nt < 16; ++nt) b1v[nt] = b1[(w << 8) + (nt << 4) + l15];
    #pragma unroll
    for (int c = 0; c < 4; ++c) b2v[c] = b2[(w << 6) + (c << 4) + l15];
    #pragma unroll
    for (int c = 0; c < 4; ++c)
        #pragma unroll
        for (int j = 0; j < 4; ++j) {
            const int rr = (kgrp << 2) + j;
            const int col = (w << 6) + (c << 4) + l15;
            const float v = y0[(row0 + rr) * Dn + col];
            yreg[c][j] = v; ksum[c][j] = 0.f; kk[c][j] = 0.f;
            out[(row0 + rr) * Dn + col] = v;
        }
    const u16* wv1 = w1p + ((w << 4) * (16 * 512)) + (lane << 3);
    const u16* wv2 = w2p + ((w << 2) * (64 * 512)) + (lane << 3);
    const int arow = l15;
    const unsigned swzA = (unsigned)((arow & 7) << 3);
    for (int step = 0; step < Tn - 1; ++step) {
        if (tid < 16)
            lds_dt[tid] = tt[(step + 1) * Bn + row0 + tid] - tt[step * Bn + row0 + tid];
        #pragma unroll 1
        for (int s = 0; s < 4; ++s) {
            const float ci = (s == 3) ? 1.0f : ((s == 0) ? 0.0f : 0.5f);
            #pragma unroll
            for (int c = 0; c < 4; ++c)
                #pragma unroll
                for (int j = 0; j < 4; ++j) {
                    const int rr = (kgrp << 2) + j;
                    const int col = (w << 6) + (c << 4) + l15;
                    lds_ys[(unsigned)((rr << 9) + col) ^ (unsigned)((rr & 7) << 3)] =
                        f2bf(yreg[c][j] + ci * kk[c][j]);
                }
            __syncthreads();
            if (s == 0) {
                #pragma unroll
                for (int j = 0; j < 4; ++j) dtv[j] = lds_dt[(kgrp << 2) + j];
            }
            f32x4 acc[16];
            #pragma unroll
            for (int nt = 0; nt < 16; ++nt)
                #pragma unroll
                for (int j = 0; j < 4; ++j) acc[nt][j] = b1v[nt];
            #pragma unroll 2
            for (int kt = 0; kt < 16; ++kt) {
                const unsigned ia = ((unsigned)((arow << 9) + (kt << 5) + (kgrp << 3))) ^ swzA;
                const s16x8 a = *(const s16x8*)&lds_ys[ia];
                #pragma unroll
                for (int nt = 0; nt < 16; ++nt) {
                    const s16x8 bfrag = *(const s16x8*)&wv1[nt * 8192 + kt * 512];
                    acc[nt] = __builtin_amdgcn_mfma_f32_16x16x32_bf16(a, bfrag, acc[nt], 0, 0, 0);
                }
            }
            #pragma unroll
            for (int nt = 0; nt < 16; ++nt)
                #pragma unroll
                for (int j = 0; j < 4; ++j) {
                    const int rr = (kgrp << 2) + j;
                    const int col = (w << 8) + (nt << 4) + l15;
                    lds_hid[(unsigned)((rr << 11) + col) ^ (unsigned)((rr & 7) << 3)] =
                        f2bf(tanh_fast(acc[nt][j]));
                }
            __syncthreads();
            f32x4 acc2[4];
            #pragma unroll
            for (int c = 0; c < 4; ++c)
                #pragma unroll
                for (int j = 0; j < 4; ++j) acc2[c][j] = 0.f;
            #pragma unroll 2
            for (int kt = 0; kt < 64; ++kt) {
                const unsigned ia = ((unsigned)((arow << 11) + (kt << 5) + (kgrp << 3))) ^ swzA;
                const s16x8 a = *(const s16x8*)&lds_hid[ia];
                #pragma unroll
                for (int c = 0; c < 4; ++c) {
                    const s16x8 bfrag = *(const s16x8*)&wv2[c * 32768 + kt * 512];
                    acc2[c] = __builtin_amdgcn_mfma_f32_16x16x32_bf16(a, bfrag, acc2[c], 0, 0, 0);
                }
            }
            const float wq = (s == 0 || s == 3) ? 1.0f : 2.0f;
            #pragma unroll
            for (int c = 0; c < 4; ++c)
                #pragma unroll
                for (int j = 0; j < 4; ++j) {
                    const float kv = dtv[j] * (acc2[c][j] + b2v[c]);
                    kk[c][j] = kv;
                    ksum[c][j] = (s == 0) ? kv : ksum[c][j] + wq * kv;
                }
        }
        #pragma unroll
        for (int c = 0; c < 4; ++c)
            #pragma unroll
            for (int j = 0; j < 4; ++j) {
                const int rr = (kgrp << 2) + j;
                const int col = (w << 6) + (c << 4) + l15;
                yreg[c][j] += ksum[c][j] * (1.0f / 6.0f);
                out[((step + 1) * Bn + row0 + rr) * Dn + col] = yreg[c][j];
            }
    }
}

extern "C" void kernel_launch(void* const* d_in, const int* in_sizes, int n_in,
                              void* d_out, int out_size, void* d_ws, size_t ws_size,
                              hipStream_t stream) {
    const float* y0 = (const float*)d_in[0];
    const float* tt = (const float*)d_in[1];
    const float* W1 = (const float*)d_in[2];
    const float* b1 = (const float*)d_in[3];
    const float* W2 = (const float*)d_in[4];
    const float* b2 = (const float*)d_in[5];
    float* out = (float*)d_out;
    char* ws = (char*)d_ws;

    const size_t sz_fl = (size_t)64 * 1024;                 // per flag array
    const size_t sz_x = 4096;                                // xslot(1K)+xmode+xepoch
    const size_t sz_w = (size_t)Dn * Hn * 2;                // 2MB each
    const size_t sz_ybuf = (size_t)32 * 16 * 512 * 2;       // 512KB
    const size_t sz_kpart = (size_t)32 * 16 * 16 * 1024;    // 8MB
    const size_t needed = 2 * sz_fl + sz_x + 2 * sz_w + sz_ybuf + sz_kpart + 4096;

    u32* flags1 = (u32*)ws;
    u32* flags2 = (u32*)(ws + sz_fl);
    u32* xslot = (u32*)(ws + 2 * sz_fl);
    u32* xmode = (u32*)(ws + 2 * sz_fl + 1024);
    u32* xepoch = (u32*)(ws + 2 * sz_fl + 1088);
    u16* w1p = (u16*)(ws + 2 * sz_fl + sz_x);
    u16* w2p = (u16*)(ws + 2 * sz_fl + sz_x + sz_w);
    u16* ybuf = (u16*)(ws + 2 * sz_fl + sz_x + 2 * sz_w);
    u16* kpart = (u16*)(ws + 2 * sz_fl + sz_x + 2 * sz_w + sz_ybuf);

    if (ws_size >= needed) {
        hipMemsetAsync(ws, 0, 2 * sz_fl + sz_x, stream);
        pack_w<<<4096, 256, 0, stream>>>(W1, W2, w1p, w2p);
        void* args[] = {&y0, &tt, &b1, &b2, &w1p, &w2p, &out, &ybuf, &kpart,
                        &flags1, &flags2, &xslot, &xmode, &xepoch};
        hipLaunchCooperativeKernel((void*)ode_v19, dim3(256), dim3(512), args, 0, stream);
    } else {
        u16* f1 = (u16*)ws;
        u16* f2 = f1 + (size_t)Dn * Hn;
        pack_w<<<4096, 256, 0, stream>>>(W1, W2, f1, f2);
        ode_rk4_fb<<<32, 512, 0, stream>>>(y0, tt, b1, b2, f1, f2, out);
    }
}

// Round 20
// 1772.436 us; speedup vs baseline: 3.2985x; 3.2985x over previous
//
#include <hip/hip_runtime.h>

#define Tn 64
#define Bn 512
#define Dn 512
#define Hn 2048

typedef __attribute__((ext_vector_type(8))) short s16x8;
typedef __attribute__((ext_vector_type(4))) float f32x4;
typedef __attribute__((ext_vector_type(4))) unsigned int u32x4;
typedef unsigned int u32;
typedef unsigned long long u64;
typedef unsigned short u16;

__device__ __forceinline__ u16 f2bf(float f) {
    u32 u = __builtin_bit_cast(u32, f);
    return (u16)((u + 0x7fffu + ((u >> 16) & 1u)) >> 16);
}
__device__ __forceinline__ float bf2f(u32 v) {
    return __builtin_bit_cast(float, v << 16);
}
__device__ __forceinline__ float tanh_fast(float x) {
    float e = __builtin_amdgcn_exp2f(x * 2.885390081777927f);
    return 1.0f - 2.0f * __builtin_amdgcn_rcpf(e + 1.0f);
}
__device__ __forceinline__ u32 agent_ld(const u32* p) {
    return __hip_atomic_load((u32*)p, __ATOMIC_RELAXED, __HIP_MEMORY_SCOPE_AGENT);
}
__device__ __forceinline__ void agent_st(u32* p, u32 v) {
    __hip_atomic_store(p, v, __ATOMIC_RELAXED, __HIP_MEMORY_SCOPE_AGENT);
}
__device__ __forceinline__ u32 get_xcc() {
    u32 x;
    asm volatile("s_getreg_b32 %0, hwreg(HW_REG_XCC_ID)" : "=s"(x));
    return x & 0xffu;
}

// ---- bulk-data ops: XL=true -> XCD-local L2 (sc0); XL=false -> device scope ----
template<bool XL>
__device__ __forceinline__ void eld128(u32x4& d, u32 vo, const void* base) {
    if constexpr (XL)
        asm volatile("global_load_dwordx4 %0, %1, %2 sc0"
                     : "=v"(d) : "v"(vo), "s"(base) : "memory");
    else
        asm volatile("global_load_dwordx4 %0, %1, %2 sc0 sc1 nt"
                     : "=v"(d) : "v"(vo), "s"(base) : "memory");
}
template<bool XL>
__device__ __forceinline__ void eld32(u32& d, u32 vo, const void* base) {
    if constexpr (XL)
        asm volatile("global_load_dword %0, %1, %2 sc0"
                     : "=v"(d) : "v"(vo), "s"(base) : "memory");
    else
        asm volatile("global_load_dword %0, %1, %2 sc0 sc1 nt"
                     : "=v"(d) : "v"(vo), "s"(base) : "memory");
}
template<bool XL>
__device__ __forceinline__ void est64(void* pa, u64 v) {
    if constexpr (XL)
        asm volatile("global_store_dwordx2 %0, %1, off sc0" :: "v"(pa), "v"(v) : "memory");
    else
        asm volatile("global_store_dwordx2 %0, %1, off sc0 sc1" :: "v"(pa), "v"(v) : "memory");
}
template<bool XL>
__device__ __forceinline__ void est32(void* pa, u32 v) {
    if constexpr (XL)
        asm volatile("global_store_dword %0, %1, off sc0" :: "v"(pa), "v"(v) : "memory");
    else
        asm volatile("global_store_dword %0, %1, off sc0 sc1" :: "v"(pa), "v"(v) : "memory");
}

// Pack W1 (512x2048) and W2 (2048x512), f32 row-major -> bf16 MFMA-B-fragment order.
__global__ void pack_w(const float* __restrict__ W1, const float* __restrict__ W2,
                       u16* __restrict__ w1p, u16* __restrict__ w2p) {
    const int i = blockIdx.x * 256 + threadIdx.x;
    const int e = i & 7;
    const int lane = (i >> 3) & 63;
    const int krem = ((lane >> 4) << 3) + e;
    const int ncol = lane & 15;
    {   // W1: K=512 (16 ktiles), N=2048 (128 ntiles)
        const int kt = (i >> 9) & 15, nt = i >> 13;
        const int k = (kt << 5) + krem, n = (nt << 4) + ncol;
        w1p[i] = f2bf(W1[k * Hn + n]);
    }
    {   // W2: K=2048 (64 ktiles), N=512 (32 ntiles)
        const int kt = (i >> 9) & 63, nt = i >> 15;
        const int k = (kt << 5) + krem, n = (nt << 4) + ncol;
        w2p[i] = f2bf(W2[k * Dn + n]);
    }
}

// ---- helpers (v9-proven) ----

template<bool XL>
__device__ __forceinline__ void stage_a(const u32* ybrC, char* ldsA, int tid) {
    u32x4 d0, d1;
    const u32 vo = (u32)(tid << 5);
    eld128<XL>(d0, vo, ybrC);
    eld128<XL>(d1, vo + 16u, ybrC);
    asm volatile("s_waitcnt vmcnt(0)" : "+v"(d0), "+v"(d1) :: "memory");
    const u32 row = (u32)(tid >> 5);
    const u32 dst = vo ^ ((row & 7u) << 4);
    *(u32x4*)(ldsA + dst) = d0;
    *(u32x4*)(ldsA + (dst ^ 16u)) = d1;
}

__device__ __forceinline__ void stage_a0(const float* y0, int c, char* ldsA, int tid) {
    const float4* yc = (const float4*)(y0 + (size_t)(c << 4) * Dn);
    #pragma unroll
    for (int it = 0; it < 4; ++it) {
        const int idx = (it << 9) + tid;            // over [16 rows][128 f4]
        const float4 v = yc[idx];
        const u32 row = (u32)idx >> 7;
        u64 pk = (u64)((u32)f2bf(v.x) | ((u32)f2bf(v.y) << 16)) |
                 ((u64)((u32)f2bf(v.z) | ((u32)f2bf(v.w) << 16)) << 32);
        const u32 dst = (row * 1024u + ((u32)(idx & 127) << 3)) ^ ((row & 7u) << 4);
        *(u64*)(ldsA + dst) = pk;
    }
}

__device__ __forceinline__ void gemm1(const char* ldsA, char* ldsH,
                                      const s16x8 (&w1r)[16], float bia,
                                      u32 abase, u32 aswz, int w, int l15, int kg) {
    f32x4 g1 = f32x4{bia, bia, bia, bia};
    #pragma unroll
    for (int kt = 0; kt < 16; ++kt) {
        const s16x8 a = *(const s16x8*)(ldsA + ((abase + ((u32)kt << 6)) ^ aswz));
        g1 = __builtin_amdgcn_mfma_f32_16x16x32_bf16(a, w1r[kt], g1, 0, 0, 0);
    }
    #pragma unroll
    for (int j = 0; j < 4; ++j) {
        const u32 row = (u32)((kg << 2) + j);
        const u32 bo = (row * 256u + (((u32)(w << 4) + (u32)l15) << 1)) ^ ((row & 7u) << 4);
        *(u16*)(ldsH + bo) = f2bf(tanh_fast(g1[j]));
    }
}

template<bool XL>
__device__ __forceinline__ void gemm2_store(const char* ldsH, char* kpC,
                                            const s16x8 (&w2r)[4][4],
                                            u32 hbase, u32 aswz, int w, int l15,
                                            int kg, int h) {
    f32x4 acc[4];
    #pragma unroll
    for (int c = 0; c < 4; ++c) acc[c] = f32x4{0.f, 0.f, 0.f, 0.f};
    #pragma unroll
    for (int ks2 = 0; ks2 < 4; ++ks2) {
        const s16x8 ha = *(const s16x8*)(ldsH + ((hbase + ((u32)ks2 << 6)) ^ aswz));
        #pragma unroll
        for (int c = 0; c < 4; ++c)
            acc[c] = __builtin_amdgcn_mfma_f32_16x16x32_bf16(ha, w2r[c][ks2], acc[c], 0, 0, 0);
    }
    // partial block (o, h): [32 cols][16 rows] bf16 col-major, 1 KB
    #pragma unroll
    for (int c = 0; c < 4; ++c) {
        const int nt = (w << 2) + c;
        const int o = nt >> 1;
        const int sc2 = ((nt & 1) << 4) + l15;
        u64 pk = (u64)((u32)f2bf(acc[c][0]) | ((u32)f2bf(acc[c][1]) << 16)) |
                 ((u64)((u32)f2bf(acc[c][2]) | ((u32)f2bf(acc[c][3]) << 16)) << 32);
        void* pa = kpC + (size_t)((o << 4) + h) * 1024 + (u32)((sc2 << 5) + (kg << 3));
        est64<XL>(pa, pk);
    }
}

// post-gather RK4 update + y_in broadcast (no loads here)
template<bool XL>
__device__ __forceinline__ void owner_update(int s, float& ys, float& ks, float& dtv,
                                             int brow, float sacc, u32* ybrC,
                                             const float* tt, float* out, float b2c,
                                             int colg, int sc, int rm, int h) {
    const int step = s >> 2, sub = s & 3;
    if (sub == 0)
        dtv = tt[(step + 1) * Bn + brow] - tt[step * Bn + brow];
    const float kk = dtv * (sacc + b2c);
    float yin;
    if (sub == 0)      { ks = kk;         yin = ys + 0.5f * kk; }
    else if (sub == 1) { ks += 2.f * kk;  yin = ys + 0.5f * kk; }
    else if (sub == 2) { ks += 2.f * kk;  yin = ys + kk; }
    else {
        ks += kk; ys += ks * (1.f / 6.f); yin = ys;
        __builtin_nontemporal_store(ys, &out[((step + 1) * Bn + brow) * Dn + colg]);
    }
    if (s < 251) {
        const u32 my = (u32)f2bf(yin);
        const u32 pu = (u32)__shfl_xor((int)my, 16, 64);
        if ((sc & 1) == 0) {
            u32* ba = ybrC + (rm << 8) + (h << 4) + (sc >> 1);
            est32<XL>(ba, my | (pu << 16));
        }
    }
}

// v18 loop: v12 + batched dual-chunk gather with split waitcnt.
template<bool XL>
__device__ __forceinline__ void ode_loop(
    const float* y0, const float* tt, float* out,
    char* A0, char* A1, char* H0, char* H1,
    const s16x8 (&w1r)[16], const s16x8 (&w2r)[4][4],
    float bia, float b2c, u32 abase, u32 aswz, u32 hbase,
    u32* ybr0, u32* ybr1, char* kp0, char* kp1,
    u32* fl1c0, u32* fl1c1, u32* fl2c0, u32* fl2c1,
    int c0, int c1, int brow0, int brow1, int colg,
    int tid, int w, int l15, int kg, int sc, int rm, int h,
    float ys0, float ys1) {
    float ks0 = 0.f, ks1 = 0.f, dt0 = 0.f, dt1 = 0.f;
    #pragma unroll 1
    for (int s = 0; s < 252; ++s) {
        // ---- SYNC-A: both chunks' y_in ready; stage both A-tiles ----
        if (s == 0) {
            stage_a0(y0, c0, A0, tid);
            stage_a0(y0, c1, A1, tid);
        } else {
            if (tid < 32) {
                u32* f = (tid < 16) ? (fl2c0 + tid) : (fl2c1 + (tid & 15));
                while (agent_ld(f) < (u32)s) __builtin_amdgcn_s_sleep(1);
            }
            __syncthreads();
            stage_a<XL>(ybr0, A0, tid);
            stage_a<XL>(ybr1, A1, tid);
        }
        __syncthreads();
        // ---- GEMM1 both chunks ----
        gemm1(A0, H0, w1r, bia, abase, aswz, w, l15, kg);
        gemm1(A1, H1, w1r, bia, abase, aswz, w, l15, kg);
        __syncthreads();
        // ---- GEMM2 both chunks + partial stores; publish fl1 pair ----
        gemm2_store<XL>(H0, kp0, w2r, hbase, aswz, w, l15, kg, h);
        gemm2_store<XL>(H1, kp1, w2r, hbase, aswz, w, l15, kg, h);
        asm volatile("s_waitcnt vmcnt(0)" ::: "memory");
        __syncthreads();
        if (tid == 0) {
            agent_st(fl1c0 + h, (u32)(s + 1));
            agent_st(fl1c1 + h, (u32)(s + 1));
        }
        // ---- SYNC-B: all partials ready (one merged poll) ----
        if (tid < 32) {
            u32* f = (tid < 16) ? (fl1c0 + tid) : (fl1c1 + (tid & 15));
            while (agent_ld(f) < (u32)(s + 1)) __builtin_amdgcn_s_sleep(1);
        }
        __syncthreads();
        // ---- batched gather (both chunks, split waitcnt) ----
        float sacc0 = 0.f, sacc1 = 0.f;
        {
            const u32 bo = ((u32)h << 14) + (u32)((sc << 5) + ((rm >> 1) << 2));
            u32 a0,a1,a2,a3,a4,a5,a6,a7,a8,a9,aa,ab,ac,ad,ae,af;
            u32 b0,b1,b2,b3,b4,b5,b6,b7,b8,b9,ba,bb,bc,bd,be,bf;
            eld32<XL>(a0, bo + (0u << 10), kp0);  eld32<XL>(a1, bo + (1u << 10), kp0);
            eld32<XL>(a2, bo + (2u << 10), kp0);  eld32<XL>(a3, bo + (3u << 10), kp0);
            eld32<XL>(a4, bo + (4u << 10), kp0);  eld32<XL>(a5, bo + (5u << 10), kp0);
            eld32<XL>(a6, bo + (6u << 10), kp0);  eld32<XL>(a7, bo + (7u << 10), kp0);
            eld32<XL>(a8, bo + (8u << 10), kp0);  eld32<XL>(a9, bo + (9u << 10), kp0);
            eld32<XL>(aa, bo + (10u << 10), kp0); eld32<XL>(ab, bo + (11u << 10), kp0);
            eld32<XL>(ac, bo + (12u << 10), kp0); eld32<XL>(ad, bo + (13u << 10), kp0);
            eld32<XL>(ae, bo + (14u << 10), kp0); eld32<XL>(af, bo + (15u << 10), kp0);
            eld32<XL>(b0, bo + (0u << 10), kp1);  eld32<XL>(b1, bo + (1u << 10), kp1);
            eld32<XL>(b2, bo + (2u << 10), kp1);  eld32<XL>(b3, bo + (3u << 10), kp1);
            eld32<XL>(b4, bo + (4u << 10), kp1);  eld32<XL>(b5, bo + (5u << 10), kp1);
            eld32<XL>(b6, bo + (6u << 10), kp1);  eld32<XL>(b7, bo + (7u << 10), kp1);
            eld32<XL>(b8, bo + (8u << 10), kp1);  eld32<XL>(b9, bo + (9u << 10), kp1);
            eld32<XL>(ba, bo + (10u << 10), kp1); eld32<XL>(bb, bo + (11u << 10), kp1);
            eld32<XL>(bc, bo + (12u << 10), kp1); eld32<XL>(bd, bo + (13u << 10), kp1);
            eld32<XL>(be, bo + (14u << 10), kp1); eld32<XL>(bf, bo + (15u << 10), kp1);
            // wait first 16 (chunk0), accumulate, then drain rest (chunk1)
            asm volatile("s_waitcnt vmcnt(16)"
                         : "+v"(a0),"+v"(a1),"+v"(a2),"+v"(a3),
                           "+v"(a4),"+v"(a5),"+v"(a6),"+v"(a7),
                           "+v"(a8),"+v"(a9),"+v"(aa),"+v"(ab),
                           "+v"(ac),"+v"(ad),"+v"(ae),"+v"(af) :: "memory");
            const bool hi = (rm & 1);
#define ACCA(d) sacc0 += bf2f(hi ? ((d) >> 16) : ((d) & 0xffffu))
#define ACCB(d) sacc1 += bf2f(hi ? ((d) >> 16) : ((d) & 0xffffu))
            ACCA(a0); ACCA(a1); ACCA(a2); ACCA(a3);
            ACCA(a4); ACCA(a5); ACCA(a6); ACCA(a7);
            ACCA(a8); ACCA(a9); ACCA(aa); ACCA(ab);
            ACCA(ac); ACCA(ad); ACCA(ae); ACCA(af);
            asm volatile("s_waitcnt vmcnt(0)"
                         : "+v"(b0),"+v"(b1),"+v"(b2),"+v"(b3),
                           "+v"(b4),"+v"(b5),"+v"(b6),"+v"(b7),
                           "+v"(b8),"+v"(b9),"+v"(ba),"+v"(bb),
                           "+v"(bc),"+v"(bd),"+v"(be),"+v"(bf) :: "memory");
            ACCB(b0); ACCB(b1); ACCB(b2); ACCB(b3);
            ACCB(b4); ACCB(b5); ACCB(b6); ACCB(b7);
            ACCB(b8); ACCB(b9); ACCB(ba); ACCB(bb);
            ACCB(bc); ACCB(bd); ACCB(be); ACCB(bf);
#undef ACCA
#undef ACCB
        }
        // ---- RK4 update + broadcast, both chunks (v12 placement incl. out) ----
        owner_update<XL>(s, ys0, ks0, dt0, brow0, sacc0, ybr0,
                         tt, out, b2c, colg, sc, rm, h);
        owner_update<XL>(s, ys1, ks1, dt1, brow1, sacc1, ybr1,
                         tt, out, b2c, colg, sc, rm, h);
        if (s < 251) {
            asm volatile("s_waitcnt vmcnt(0)" ::: "memory");
            __syncthreads();
            if (tid == 0) {
                agent_st(fl2c0 + h, (u32)(s + 1));
                agent_st(fl2c1 + h, (u32)(s + 1));
            }
        }
    }
}

// v18 (final): v12 + batched dual-chunk gather (split waitcnt). 256 WGs =
// 16 pairs x 16 slices (p=bid&15 -> XCD pinning, runtime-verified).
__launch_bounds__(512, 2)
__global__ void ode_v18(const float* __restrict__ y0, const float* __restrict__ tt,
                        const float* __restrict__ b1, const float* __restrict__ b2,
                        const u16* __restrict__ w1p, const u16* __restrict__ w2p,
                        float* __restrict__ out, u16* __restrict__ ybuf,
                        u16* __restrict__ kpart, u32* __restrict__ flags1,
                        u32* __restrict__ flags2, u32* __restrict__ xslot,
                        u32* __restrict__ xmode) {
    __shared__ u16 lds_A0[16 * 512], lds_A1[16 * 512];   // 16KB each
    __shared__ u16 lds_H0[16 * 128], lds_H1[16 * 128];   // 4KB each
    __shared__ u32 smode;
    char* A0 = (char*)lds_A0; char* A1 = (char*)lds_A1;
    char* H0 = (char*)lds_H0; char* H1 = (char*)lds_H1;

    const int tid = threadIdx.x;
    const int w = tid >> 6, lane = tid & 63, l15 = lane & 15, kg = lane >> 4;
    const int p = blockIdx.x & 15, h = blockIdx.x >> 4;   // pair -> XCD pinning
    const int c0 = p << 1, c1 = c0 + 1;

    // ---- runtime XCD-affinity detection (v9-proven, agent-scope) ----
    if (tid == 0) {
        agent_st(xslot + (p << 4) + h, get_xcc() + 1u);
        if (h == 0) {
            u32 ref = 0; bool same = true;
            #pragma unroll 1
            for (int i = 0; i < 16; ++i) {
                u32 v;
                while ((v = agent_ld(xslot + (p << 4) + i)) == 0u)
                    __builtin_amdgcn_s_sleep(1);
                if (i == 0) ref = v; else same = same && (v == ref);
            }
            agent_st(xmode + p, same ? 1u : 2u);
        }
        u32 m;
        while ((m = agent_ld(xmode + p)) == 0u) __builtin_amdgcn_s_sleep(1);
        smode = m;
    }

    const int sc = tid >> 4, rm = tid & 15;
    const int colg = (h << 5) + sc;
    const int brow0 = (c0 << 4) + rm, brow1 = (c1 << 4) + rm;
    const float b2c = b2[colg];
    float ys0 = y0[brow0 * Dn + colg];
    float ys1 = y0[brow1 * Dn + colg];
    __builtin_nontemporal_store(ys0, &out[brow0 * Dn + colg]);
    __builtin_nontemporal_store(ys1, &out[brow1 * Dn + colg]);

    // ---- weight preload into registers ----
    s16x8 w1r[16];
    #pragma unroll
    for (int kt = 0; kt < 16; ++kt)
        w1r[kt] = *(const s16x8*)&w1p[((size_t)((h << 3) + w) * 16 + kt) * 512 + (lane << 3)];
    s16x8 w2r[4][4];
    #pragma unroll
    for (int cc = 0; cc < 4; ++cc)
        #pragma unroll
        for (int ks2 = 0; ks2 < 4; ++ks2)
            w2r[cc][ks2] = *(const s16x8*)&w2p[((size_t)((w << 2) + cc) * 64 + (h << 2) + ks2) * 512 + (lane << 3)];
    const float bia = b1[(h << 7) + (w << 4) + l15];

    const u32 abase = (u32)l15 * 1024u + ((u32)kg << 4);
    const u32 aswz = ((u32)(l15 & 7)) << 4;
    const u32 hbase = (u32)l15 * 256u + ((u32)kg << 4);

    u32* ybr0 = (u32*)(ybuf + (size_t)c0 * 16 * 512);
    u32* ybr1 = (u32*)(ybuf + (size_t)c1 * 16 * 512);
    char* kp0 = (char*)kpart + (size_t)c0 * (256 * 1024);
    char* kp1 = (char*)kpart + (size_t)c1 * (256 * 1024);
    u32* fl1c0 = flags1 + (c0 << 4); u32* fl1c1 = flags1 + (c1 << 4);
    u32* fl2c0 = flags2 + (c0 << 4); u32* fl2c1 = flags2 + (c1 << 4);

    __syncthreads();
    const u32 mode = smode;

    if (mode == 1u)
        ode_loop<true>(y0, tt, out, A0, A1, H0, H1, w1r, w2r, bia, b2c,
                       abase, aswz, hbase, ybr0, ybr1, kp0, kp1,
                       fl1c0, fl1c1, fl2c0, fl2c1, c0, c1, brow0, brow1, colg,
                       tid, w, l15, kg, sc, rm, h, ys0, ys1);
    else
        ode_loop<false>(y0, tt, out, A0, A1, H0, H1, w1r, w2r, bia, b2c,
                        abase, aswz, hbase, ybr0, ybr1, kp0, kp1,
                        fl1c0, fl1c1, fl2c0, fl2c1, c0, c1, brow0, brow1, colg,
                        tid, w, l15, kg, sc, rm, h, ys0, ys1);
}

// ---------------- fallback: round-1 kernel (32 WGs) ----------------
__launch_bounds__(512, 2)
__global__ void ode_rk4_fb(const float* __restrict__ y0, const float* __restrict__ tt,
                           const float* __restrict__ b1, const float* __restrict__ b2,
                           const u16* __restrict__ w1p, const u16* __restrict__ w2p,
                           float* __restrict__ out) {
    __shared__ u16 lds_ys[16 * Dn];
    __shared__ u16 lds_hid[16 * Hn];
    __shared__ float lds_dt[16];
    const int tid = threadIdx.x;
    const int w = tid >> 6, lane = tid & 63, l15 = lane & 15, kgrp = lane >> 4;
    const int row0 = blockIdx.x << 4;
    float yreg[4][4], ksum[4][4], kk[4][4];
    float b1v[16], b2v[4], dtv[4];
    #pragma unroll
    for (int nt = 0; nt < 16; ++nt) b1v[nt] = b1[(w << 8) + (nt << 4) + l15];
    #pragma unroll
    for (int c = 0; c < 4; ++c) b2v[c] = b2[(w << 6) + (c << 4) + l15];
    #pragma unroll
    for (int c = 0; c < 4; ++c)
        #pragma unroll
        for (int j = 0; j < 4; ++j) {
            const int rr = (kgrp << 2) + j;
            const int col = (w << 6) + (c << 4) + l15;
            const float v = y0[(row0 + rr) * Dn + col];
            yreg[c][j] = v; ksum[c][j] = 0.f; kk[c][j] = 0.f;
            out[(row0 + rr) * Dn + col] = v;
        }
    const u16* wv1 = w1p + ((w << 4) * (16 * 512)) + (lane << 3);
    const u16* wv2 = w2p + ((w << 2) * (64 * 512)) + (lane << 3);
    const int arow = l15;
    const unsigned swzA = (unsigned)((arow & 7) << 3);
    for (int step = 0; step < Tn - 1; ++step) {
        if (tid < 16)
            lds_dt[tid] = tt[(step + 1) * Bn + row0 + tid] - tt[step * Bn + row0 + tid];
        #pragma unroll 1
        for (int s = 0; s < 4; ++s) {
            const float ci = (s == 3) ? 1.0f : ((s == 0) ? 0.0f : 0.5f);
            #pragma unroll
            for (int c = 0; c < 4; ++c)
                #pragma unroll
                for (int j = 0; j < 4; ++j) {
                    const int rr = (kgrp << 2) + j;
                    const int col = (w << 6) + (c << 4) + l15;
                    lds_ys[(unsigned)((rr << 9) + col) ^ (unsigned)((rr & 7) << 3)] =
                        f2bf(yreg[c][j] + ci * kk[c][j]);
                }
            __syncthreads();
            if (s == 0) {
                #pragma unroll
                for (int j = 0; j < 4; ++j) dtv[j] = lds_dt[(kgrp << 2) + j];
            }
            f32x4 acc[16];
            #pragma unroll
            for (int nt = 0; nt < 16; ++nt)
                #pragma unroll
                for (int j = 0; j < 4; ++j) acc[nt][j] = b1v[nt];
            #pragma unroll 2
            for (int kt = 0; kt < 16; ++kt) {
                const unsigned ia = ((unsigned)((arow << 9) + (kt << 5) + (kgrp << 3))) ^ swzA;
                const s16x8 a = *(const s16x8*)&lds_ys[ia];
                #pragma unroll
                for (int nt = 0; nt < 16; ++nt) {
                    const s16x8 bfrag = *(const s16x8*)&wv1[nt * 8192 + kt * 512];
                    acc[nt] = __builtin_amdgcn_mfma_f32_16x16x32_bf16(a, bfrag, acc[nt], 0, 0, 0);
                }
            }
            #pragma unroll
            for (int nt = 0; nt < 16; ++nt)
                #pragma unroll
                for (int j = 0; j < 4; ++j) {
                    const int rr = (kgrp << 2) + j;
                    const int col = (w << 8) + (nt << 4) + l15;
                    lds_hid[(unsigned)((rr << 11) + col) ^ (unsigned)((rr & 7) << 3)] =
                        f2bf(tanh_fast(acc[nt][j]));
                }
            __syncthreads();
            f32x4 acc2[4];
            #pragma unroll
            for (int c = 0; c < 4; ++c)
                #pragma unroll
                for (int j = 0; j < 4; ++j) acc2[c][j] = 0.f;
            #pragma unroll 2
            for (int kt = 0; kt < 64; ++kt) {
                const unsigned ia = ((unsigned)((arow << 11) + (kt << 5) + (kgrp << 3))) ^ swzA;
                const s16x8 a = *(const s16x8*)&lds_hid[ia];
                #pragma unroll
                for (int c = 0; c < 4; ++c) {
                    const s16x8 bfrag = *(const s16x8*)&wv2[c * 32768 + kt * 512];
                    acc2[c] = __builtin_amdgcn_mfma_f32_16x16x32_bf16(a, bfrag, acc2[c], 0, 0, 0);
                }
            }
            const float wq = (s == 0 || s == 3) ? 1.0f : 2.0f;
            #pragma unroll
            for (int c = 0; c < 4; ++c)
                #pragma unroll
                for (int j = 0; j < 4; ++j) {
                    const float kv = dtv[j] * (acc2[c][j] + b2v[c]);
                    kk[c][j] = kv;
                    ksum[c][j] = (s == 0) ? kv : ksum[c][j] + wq * kv;
                }
        }
        #pragma unroll
        for (int c = 0; c < 4; ++c)
            #pragma unroll
            for (int j = 0; j < 4; ++j) {
                const int rr = (kgrp << 2) + j;
                const int col = (w << 6) + (c << 4) + l15;
                yreg[c][j] += ksum[c][j] * (1.0f / 6.0f);
                out[((step + 1) * Bn + row0 + rr) * Dn + col] = yreg[c][j];
            }
    }
}

extern "C" void kernel_launch(void* const* d_in, const int* in_sizes, int n_in,
                              void* d_out, int out_size, void* d_ws, size_t ws_size,
                              hipStream_t stream) {
    const float* y0 = (const float*)d_in[0];
    const float* tt = (const float*)d_in[1];
    const float* W1 = (const float*)d_in[2];
    const float* b1 = (const float*)d_in[3];
    const float* W2 = (const float*)d_in[4];
    const float* b2 = (const float*)d_in[5];
    float* out = (float*)d_out;
    char* ws = (char*)d_ws;

    const size_t sz_fl = (size_t)64 * 1024;                 // per flag array
    const size_t sz_x = 4096;                                // xslot(1K)+xmode
    const size_t sz_w = (size_t)Dn * Hn * 2;                // 2MB each
    const size_t sz_ybuf = (size_t)32 * 16 * 512 * 2;       // 512KB
    const size_t sz_kpart = (size_t)32 * 16 * 16 * 1024;    // 8MB
    const size_t needed = 2 * sz_fl + sz_x + 2 * sz_w + sz_ybuf + sz_kpart + 4096;

    u32* flags1 = (u32*)ws;
    u32* flags2 = (u32*)(ws + sz_fl);
    u32* xslot = (u32*)(ws + 2 * sz_fl);
    u32* xmode = (u32*)(ws + 2 * sz_fl + 1024);
    u16* w1p = (u16*)(ws + 2 * sz_fl + sz_x);
    u16* w2p = (u16*)(ws + 2 * sz_fl + sz_x + sz_w);
    u16* ybuf = (u16*)(ws + 2 * sz_fl + sz_x + 2 * sz_w);
    u16* kpart = (u16*)(ws + 2 * sz_fl + sz_x + 2 * sz_w + sz_ybuf);

    if (ws_size >= needed) {
        hipMemsetAsync(ws, 0, 2 * sz_fl + sz_x, stream);
        pack_w<<<4096, 256, 0, stream>>>(W1, W2, w1p, w2p);
        void* args[] = {&y0, &tt, &b1, &b2, &w1p, &w2p, &out, &ybuf, &kpart,
                        &flags1, &flags2, &xslot, &xmode};
        hipLaunchCooperativeKernel((void*)ode_v18, dim3(256), dim3(512), args, 0, stream);
    } else {
        u16* f1 = (u16*)ws;
        u16* f2 = f1 + (size_t)Dn * Hn;
        pack_w<<<4096, 256, 0, stream>>>(W1, W2, f1, f2);
        ode_rk4_fb<<<32, 512, 0, stream>>>(y0, tt, b1, b2, f1, f2, out);
    }
}